// Round 3
// baseline (322.140 us; speedup 1.0000x reference)
//
#include <hip/hip_runtime.h>
#include <math.h>

#define Bb 8
#define Tt 256
#define MEL 128
#define Dd 192
#define NCc 20
#define ND 4                  // delta ranks (updates at t%64==0)
#define NT 32                 // theta ranks (updates at t%8==0)
#define ETAc 0.9f
#define LRc 0.1f
#define MDEC 0.99f            // 1 - ALPHA
#define EPSc 1e-5f
#define PT 2                  // pipeline rows per block
#define PTILES 128            // Tt/PT
#define RTT 8                 // retrieve rows per block
#define RTILES 32

__device__ __forceinline__ float sigmoidf_(float x) {
    return 1.0f / (1.0f + __expf(-x));
}

// coefficient of (k_i err_i^T) in M_n, valid for i<=n
__device__ __forceinline__ float memcoef(int n, int i) {
    float m = LRc, pw = LRc;
    for (int nn = i + 1; nn <= n; nn++) { pw *= ETAc; m = MDEC * m + pw; }
    return m;
}

__device__ __forceinline__ float dot4(float4 a, float4 b) {
    return a.x * b.x + a.y * b.y + a.z * b.z + a.w * b.w;
}

// ---------------------------------------------------------------------------
// prep: weight transposes + fused attn product + delta memory chain.
// grid 425 x 192:
//  [0,32)   WinT rows      [32,80)  pw1 a/g T    [80,128)  pw2T
//  [128,176) WktT          [176,224) WvtT        [224,416) WavoT col o
//  [416]    b_avo          [417,425) delta chain per b
// ---------------------------------------------------------------------------
__global__ __launch_bounds__(192) void prep(
    const float* __restrict__ W_in, const float* __restrict__ pw1_w,
    const float* __restrict__ pw2_w, const float* __restrict__ Wk_t,
    const float* __restrict__ Wv_t, const float* __restrict__ Wv_a,
    const float* __restrict__ Wo_a, const float* __restrict__ bv_a,
    const float* __restrict__ bo_a, const float* __restrict__ x,
    const float* __restrict__ b_in, const float* __restrict__ Wk_d,
    const float* __restrict__ Wv_d, const float* __restrict__ Wq_d,
    float* __restrict__ WinT, float* __restrict__ pw1aT,
    float* __restrict__ pw1gT, float* __restrict__ pw2T,
    float* __restrict__ WktT, float* __restrict__ WvtT,
    float* __restrict__ WavoT, float* __restrict__ b_avo,
    float* __restrict__ Ed_ws, float* __restrict__ Ud_ws)
{
    __shared__ __align__(16) float smem[2848];
    int blk = blockIdx.x, tid = threadIdx.x;

    if (blk < 32) {                               // WinT [192][128]
        int r0 = 4 * blk;
        if (tid < Dd) {
            float4 o;
            o.x = W_in[(r0 + 0) * Dd + tid];
            o.y = W_in[(r0 + 1) * Dd + tid];
            o.z = W_in[(r0 + 2) * Dd + tid];
            o.w = W_in[(r0 + 3) * Dd + tid];
            *(float4*)&WinT[tid * MEL + r0] = o;
        }
        return;
    }
    if (blk < 224) {                              // [192][192] transposes
        int sec = (blk - 32) / 48, r0 = 4 * ((blk - 32) % 48);
        if (tid >= Dd) return;
        if (sec == 0) {                           // pw1 -> a/g halves
            float4 a, g;
            a.x = pw1_w[(r0 + 0) * 2 * Dd + tid];       g.x = pw1_w[(r0 + 0) * 2 * Dd + Dd + tid];
            a.y = pw1_w[(r0 + 1) * 2 * Dd + tid];       g.y = pw1_w[(r0 + 1) * 2 * Dd + Dd + tid];
            a.z = pw1_w[(r0 + 2) * 2 * Dd + tid];       g.z = pw1_w[(r0 + 2) * 2 * Dd + Dd + tid];
            a.w = pw1_w[(r0 + 3) * 2 * Dd + tid];       g.w = pw1_w[(r0 + 3) * 2 * Dd + Dd + tid];
            *(float4*)&pw1aT[tid * Dd + r0] = a;
            *(float4*)&pw1gT[tid * Dd + r0] = g;
            return;
        }
        const float* src = (sec == 1) ? pw2_w : (sec == 2) ? Wk_t : Wv_t;
        float* dst = (sec == 1) ? pw2T : (sec == 2) ? WktT : WvtT;
        float4 o;
        o.x = src[(r0 + 0) * Dd + tid];
        o.y = src[(r0 + 1) * Dd + tid];
        o.z = src[(r0 + 2) * Dd + tid];
        o.w = src[(r0 + 3) * Dd + tid];
        *(float4*)&dst[tid * Dd + r0] = o;
        return;
    }
    if (blk < 416) {                              // WavoT[o][m] = (Wv_a@Wo_a)[m][o]
        int o = blk - 224;
        float* col = smem;
        if (tid < Dd) col[tid] = Wo_a[tid * Dd + o];
        __syncthreads();
        if (tid < Dd) {
            const float4* row4 = (const float4*)&Wv_a[tid * Dd];
            float s = 0.f;
            #pragma unroll 4
            for (int kk = 0; kk < 48; kk++) s += dot4(row4[kk], ((float4*)col)[kk]);
            WavoT[o * Dd + tid] = s;
        }
        return;
    }
    if (blk == 416) {                             // b_avo = bv_a @ Wo_a + bo_a
        if (tid < Dd) {
            float s = bo_a[tid];
            for (int m = 0; m < Dd; m++) s += bv_a[m] * Wo_a[m * Dd + tid];
            b_avo[tid] = s;
        }
        return;
    }

    // ---- delta chain for batch b ----
    int b = blk - 417;
    float* XR4 = smem;             // [4][128]
    float* XP4 = smem + 512;       // [4][192]
    float* K4  = XP4 + 4 * Dd;     // [4][192]
    float* V4  = K4 + 4 * Dd;      // [4][192]  (err after recurrence)
    float* G   = V4 + 4 * Dd;      // [16]
    float* mc  = G + 16;           // [16]

    if (tid < 128) {
        int i = tid >> 5, c = tid & 31;
        ((float4*)(XR4 + i * MEL))[c] =
            ((const float4*)&x[((size_t)b * Tt + 64 * i) * MEL])[c];
    }
    __syncthreads();
    if (tid < Dd) {                               // xp = x @ W_in + b_in
        float a0 = b_in[tid], a1 = a0, a2 = a0, a3 = a0;
        for (int d = 0; d < MEL; d++) {
            float w = W_in[d * Dd + tid];
            a0 += XR4[d] * w;            a1 += XR4[MEL + d] * w;
            a2 += XR4[2 * MEL + d] * w;  a3 += XR4[3 * MEL + d] * w;
        }
        XP4[tid] = a0; XP4[Dd + tid] = a1; XP4[2 * Dd + tid] = a2; XP4[3 * Dd + tid] = a3;
    }
    __syncthreads();
    if (tid < Dd) {                               // k,v projections
        float k0 = 0, k1 = 0, k2 = 0, k3 = 0, v0 = 0, v1 = 0, v2 = 0, v3 = 0;
        for (int d = 0; d < Dd; d++) {
            float wk = Wk_d[d * Dd + tid], wv = Wv_d[d * Dd + tid];
            float x0 = XP4[d], x1 = XP4[Dd + d], x2 = XP4[2 * Dd + d], x3 = XP4[3 * Dd + d];
            k0 += x0 * wk; k1 += x1 * wk; k2 += x2 * wk; k3 += x3 * wk;
            v0 += x0 * wv; v1 += x1 * wv; v2 += x2 * wv; v3 += x3 * wv;
        }
        K4[tid] = k0; K4[Dd + tid] = k1; K4[2 * Dd + tid] = k2; K4[3 * Dd + tid] = k3;
        V4[tid] = v0; V4[Dd + tid] = v1; V4[2 * Dd + tid] = v2; V4[3 * Dd + tid] = v3;
    }
    __syncthreads();
    if (tid < 16) {                               // Gram + coefficient table
        int i = tid >> 2, j = tid & 3;
        float s = 0.f;
        for (int d = 0; d < Dd; d++) s += K4[i * Dd + d] * K4[j * Dd + d];
        G[tid] = s;
        mc[tid] = (j <= i) ? memcoef(i, j) : 0.f;  // mc[n=i][i=j]
    }
    __syncthreads();
    for (int i = 1; i < ND; i++) {                // err recurrence
        if (tid < Dd) {
            float acc = V4[i * Dd + tid];
            for (int m = 0; m < i; m++)
                acc -= mc[(i - 1) * ND + m] * G[i * ND + m] * V4[m * Dd + tid];
            V4[i * Dd + tid] = acc;
        }
        __syncthreads();
    }
    if (tid < Dd) {                               // u_i = Wq_d @ k_i ; store err,u
        float u0 = 0, u1 = 0, u2 = 0, u3 = 0;
        const float4* row4 = (const float4*)&Wq_d[tid * Dd];
        #pragma unroll 4
        for (int kk = 0; kk < 48; kk++) {
            float4 w = row4[kk];
            u0 += dot4(w, ((float4*)K4)[kk]);
            u1 += dot4(w, ((float4*)(K4 + Dd))[kk]);
            u2 += dot4(w, ((float4*)(K4 + 2 * Dd))[kk]);
            u3 += dot4(w, ((float4*)(K4 + 3 * Dd))[kk]);
        }
        Ud_ws[(b * ND + 0) * Dd + tid] = u0;
        Ud_ws[(b * ND + 1) * Dd + tid] = u1;
        Ud_ws[(b * ND + 2) * Dd + tid] = u2;
        Ud_ws[(b * ND + 3) * Dd + tid] = u3;
        for (int i = 0; i < ND; i++) Ed_ws[(b * ND + i) * Dd + tid] = V4[i * Dd + tid];
    }
}

// ---------------------------------------------------------------------------
// pipeline: grid B*128 (2 rows/block), 192 threads. Produces x3 and (tile%4==0)
// theta k/v for the update row. q-projections eliminated via u-vectors.
// ---------------------------------------------------------------------------
__global__ __launch_bounds__(192) void pipeline(
    const float* __restrict__ x, const float* __restrict__ b_in,
    const float* __restrict__ ln1_g, const float* __restrict__ ln1_b,
    const float* __restrict__ pw1_b, const float* __restrict__ dw_w,
    const float* __restrict__ dw_b, const float* __restrict__ bn_s,
    const float* __restrict__ bn_b, const float* __restrict__ pw2_b,
    const float* __restrict__ WinT, const float* __restrict__ WavoT,
    const float* __restrict__ b_avo, const float* __restrict__ pw1aT,
    const float* __restrict__ pw1gT, const float* __restrict__ pw2T,
    const float* __restrict__ WktT, const float* __restrict__ WvtT,
    const float* __restrict__ Ed_ws, const float* __restrict__ Ud_ws,
    float* __restrict__ x3_ws, float* __restrict__ Kt_ws, float* __restrict__ Et_ws)
{
    int blk = blockIdx.x;
    int b = blk >> 7, tile = blk & 127;
    int t0 = tile * PT, n = tile >> 5;     // delta epoch, tile-uniform
    int tid = threadIdx.x;

    __shared__ __align__(16) float XR[PT][MEL];
    __shared__ __align__(16) float XP[PT][Dd];
    __shared__ __align__(16) float ED[ND][Dd], UD[ND][Dd];
    __shared__ __align__(16) float X1[PT][Dd], X2[PT][Dd];
    __shared__ __align__(16) float LNX[PT][Dd], HG[PT][Dd], X3s[PT][Dd];
    __shared__ float WQs[PT * ND];
    __shared__ float mv[PT][2];

    if (tid < 64) {
        int r = tid >> 5, c = tid & 31;
        ((float4*)XR[r])[c] = ((const float4*)&x[((size_t)b * Tt + t0 + r) * MEL])[c];
    }
    for (int q = tid; q < ND * 48 * 2; q += 192) {
        int which = q >= ND * 48;
        int qq = which ? q - ND * 48 : q;
        int i = qq / 48, c = qq - i * 48;
        if (!which) ((float4*)ED[i])[c] = ((const float4*)&Ed_ws[(b * ND + i) * Dd])[c];
        else        ((float4*)UD[i])[c] = ((const float4*)&Ud_ws[(b * ND + i) * Dd])[c];
    }
    __syncthreads();

    // xp = x @ W_in + b_in
    if (tid < Dd) {
        float a0 = b_in[tid], a1 = a0;
        const float4* w4 = (const float4*)&WinT[tid * MEL];
        #pragma unroll 4
        for (int kk = 0; kk < MEL / 4; kk++) {
            float4 w = w4[kk];
            a0 += dot4(w, ((float4*)XR[0])[kk]);
            a1 += dot4(w, ((float4*)XR[1])[kk]);
        }
        XP[0][tid] = a0; XP[1][tid] = a1;
    }
    __syncthreads();

    // delta dots: WQs[r][i] = (xp_r . u_i) * mc[n][i]
    if (tid < 128) {
        int r = tid >> 6, i = (tid >> 4) & 3, c = tid & 15;
        float s = 0.f;
        const float* xp = XP[r];
        const float* u = UD[i];
        #pragma unroll
        for (int j = 0; j < 12; j++) s += xp[c * 12 + j] * u[c * 12 + j];
        s += __shfl_down(s, 8, 16);
        s += __shfl_down(s, 4, 16);
        s += __shfl_down(s, 2, 16);
        s += __shfl_down(s, 1, 16);
        if (c == 0) {
            float coef = (i <= n) ? memcoef(n, i) : 0.f;
            WQs[r * ND + i] = s * coef;
        }
    }
    __syncthreads();

    // x1 = xp + 0.5 * sum_i WQs * err_i
    if (tid < Dd) {
        #pragma unroll
        for (int r = 0; r < PT; r++) {
            float dout = WQs[r * ND + 0] * ED[0][tid] + WQs[r * ND + 1] * ED[1][tid]
                       + WQs[r * ND + 2] * ED[2][tid] + WQs[r * ND + 3] * ED[3][tid];
            X1[r][tid] = XP[r][tid] + 0.5f * dout;
        }
    }
    __syncthreads();

    // x2 = x1 + x1 @ (Wv_a Wo_a) + b_avo
    if (tid < Dd) {
        float a0 = b_avo[tid], a1 = a0;
        const float4* w4 = (const float4*)&WavoT[tid * Dd];
        #pragma unroll 4
        for (int kk = 0; kk < 48; kk++) {
            float4 w = w4[kk];
            a0 += dot4(w, ((float4*)X1[0])[kk]);
            a1 += dot4(w, ((float4*)X1[1])[kk]);
        }
        X2[0][tid] = X1[0][tid] + a0;
        X2[1][tid] = X1[1][tid] + a1;
    }
    __syncthreads();

    // LN1
    if (tid < 64) {
        int r = tid >> 5, j = tid & 31;
        float s = 0.f, sq = 0.f;
        for (int d = j; d < Dd; d += 32) { float v = X2[r][d]; s += v; sq += v * v; }
        for (int off = 16; off > 0; off >>= 1) {
            s += __shfl_down(s, off, 32); sq += __shfl_down(sq, off, 32);
        }
        if (j == 0) {
            float mean = s / Dd;
            mv[r][0] = mean;
            mv[r][1] = rsqrtf(sq / Dd - mean * mean + EPSc);
        }
    }
    __syncthreads();
    if (tid < Dd) {
        float g = ln1_g[tid], bb = ln1_b[tid];
        #pragma unroll
        for (int r = 0; r < PT; r++)
            LNX[r][tid] = (X2[r][tid] - mv[r][0]) * mv[r][1] * g + bb;
    }
    __syncthreads();

    // pw1 dual + GLU + dw + bn + silu
    if (tid < Dd) {
        float ba = pw1_b[tid], bg = pw1_b[tid + Dd];
        float aa0 = ba, aa1 = ba, gg0 = bg, gg1 = bg;
        const float4* wa4 = (const float4*)&pw1aT[tid * Dd];
        const float4* wg4 = (const float4*)&pw1gT[tid * Dd];
        #pragma unroll 4
        for (int kk = 0; kk < 48; kk++) {
            float4 wa = wa4[kk], wg = wg4[kk];
            float4 l0 = ((float4*)LNX[0])[kk], l1 = ((float4*)LNX[1])[kk];
            aa0 += dot4(wa, l0); aa1 += dot4(wa, l1);
            gg0 += dot4(wg, l0); gg1 += dot4(wg, l1);
        }
        float dww = dw_w[tid], dwb = dw_b[tid], bns = bn_s[tid], bnb = bn_b[tid];
        float h0 = aa0 * sigmoidf_(gg0);
        h0 = h0 * dww + dwb; h0 = h0 * bns + bnb; h0 = h0 * sigmoidf_(h0);
        float h1 = aa1 * sigmoidf_(gg1);
        h1 = h1 * dww + dwb; h1 = h1 * bns + bnb; h1 = h1 * sigmoidf_(h1);
        HG[0][tid] = h0; HG[1][tid] = h1;
    }
    __syncthreads();

    // pw2 + residual -> x3
    if (tid < Dd) {
        float a0 = pw2_b[tid], a1 = a0;
        const float4* w4 = (const float4*)&pw2T[tid * Dd];
        #pragma unroll 4
        for (int kk = 0; kk < 48; kk++) {
            float4 w = w4[kk];
            a0 += dot4(w, ((float4*)HG[0])[kk]);
            a1 += dot4(w, ((float4*)HG[1])[kk]);
        }
        float v0 = X2[0][tid] + a0, v1 = X2[1][tid] + a1;
        X3s[0][tid] = v0; X3s[1][tid] = v1;
        x3_ws[((size_t)b * Tt + t0 + 0) * Dd + tid] = v0;
        x3_ws[((size_t)b * Tt + t0 + 1) * Dd + tid] = v1;
    }

    // theta k/v for update row (t0%8==0 <=> tile%4==0; row 0)
    if ((tile & 3) == 0) {
        __syncthreads();
        if (tid < Dd) {
            int i8 = tile >> 2;
            const float4* wk = (const float4*)&WktT[tid * Dd];
            const float4* wv = (const float4*)&WvtT[tid * Dd];
            float ak = 0.f, av = 0.f;
            #pragma unroll 4
            for (int kk = 0; kk < 48; kk++) {
                float4 xv = ((float4*)X3s[0])[kk];
                ak += dot4(wk[kk], xv);
                av += dot4(wv[kk], xv);
            }
            Kt_ws[(b * NT + i8) * Dd + tid] = ak;
            Et_ws[(b * NT + i8) * Dd + tid] = av;
        }
    }
}

// ---------------------------------------------------------------------------
// theta_solve: grid B*5. role 0: Gram + 31-step err recurrence (rewrites Et).
// roles 1..4: u~_i = Wq_t @ k_i for 8 i's each (parallel, K-only).
// ---------------------------------------------------------------------------
__global__ __launch_bounds__(192) void theta_solve(
    const float* __restrict__ Wq_t, const float* __restrict__ Kt_ws,
    float* __restrict__ Et_ws, float* __restrict__ Ut_ws)
{
    int blk = blockIdx.x, b = blk / 5, role = blk % 5, tid = threadIdx.x;
    if (role == 0) {
        __shared__ __align__(16) float K[NT][Dd], E[NT][Dd];
        __shared__ float G[NT * NT], mc[NT * NT];
        for (int q = tid; q < NT * 48; q += 192) {
            int i = q / 48, c = q - i * 48;
            ((float4*)K[i])[c] = ((const float4*)&Kt_ws[(b * NT + i) * Dd])[c];
            ((float4*)E[i])[c] = ((const float4*)&Et_ws[(b * NT + i) * Dd])[c];
        }
        if (tid < NT) {
            int i = tid;
            float m = 0.f, pw = LRc;
            for (int nn = 0; nn < NT; nn++) {
                float v;
                if (nn < i) v = 0.f;
                else if (nn == i) { m = LRc; v = m; }
                else { pw *= ETAc; m = MDEC * m + pw; v = m; }
                mc[nn * NT + i] = v;
            }
        }
        __syncthreads();
        for (int p = tid; p < NT * NT; p += 192) {
            int i = p >> 5, j = p & 31;
            const float4* ki = (const float4*)K[i];
            const float4* kj = (const float4*)K[j];
            float s = 0.f;
            #pragma unroll 4
            for (int kk = 0; kk < 48; kk++) s += dot4(ki[kk], kj[kk]);
            G[p] = s;
        }
        __syncthreads();
        for (int i = 1; i < NT; i++) {
            if (tid < Dd) {
                float acc = E[i][tid];
                for (int m = 0; m < i; m++)
                    acc -= mc[(i - 1) * NT + m] * G[i * NT + m] * E[m][tid];
                E[i][tid] = acc;
            }
            __syncthreads();
        }
        if (tid < Dd)
            for (int i = 0; i < NT; i++) Et_ws[(b * NT + i) * Dd + tid] = E[i][tid];
    } else {
        __shared__ __align__(16) float K8[8][Dd];
        int i0 = (role - 1) * 8;
        for (int q = tid; q < 8 * 48; q += 192) {
            int i = q / 48, c = q - i * 48;
            ((float4*)K8[i])[c] = ((const float4*)&Kt_ws[(b * NT + i0 + i) * Dd])[c];
        }
        __syncthreads();
        if (tid < Dd) {
            float acc[8] = {};
            const float4* row4 = (const float4*)&Wq_t[tid * Dd];
            #pragma unroll 2
            for (int kk = 0; kk < 48; kk++) {
                float4 w = row4[kk];
                #pragma unroll
                for (int i = 0; i < 8; i++) acc[i] += dot4(w, ((float4*)K8[i])[kk]);
            }
            #pragma unroll
            for (int i = 0; i < 8; i++) Ut_ws[(b * NT + i0 + i) * Dd + tid] = acc[i];
        }
    }
}

// ---------------------------------------------------------------------------
// retrieve: grid B*32 (8 rows/block), 256 threads. x3.u~ dots + rank-32
// combine + LN2 + pooled accumulation. U/E streamed from global (L2-hot).
// ---------------------------------------------------------------------------
__global__ __launch_bounds__(256) void retrieve(
    const float* __restrict__ x3_ws, const float* __restrict__ Ut_ws,
    const float* __restrict__ Et_ws, const float* __restrict__ ln2_g,
    const float* __restrict__ ln2_b, float* __restrict__ pooled)
{
    int blk = blockIdx.x, b = blk >> 5, tile = blk & 31;
    int t0 = tile * RTT, n = tile;
    int tid = threadIdx.x;

    __shared__ __align__(16) float XS[RTT][Dd];
    __shared__ float WQ[RTT * NT];
    __shared__ float mv[RTT][2];

    for (int q = tid; q < RTT * 48; q += 256) {
        int r = q / 48, c = q - r * 48;
        ((float4*)XS[r])[c] = ((const float4*)&x3_ws[((size_t)b * Tt + t0 + r) * Dd])[c];
    }
    __syncthreads();

    // dots: tid = r*32 + i ; q.k_i = x3 . u~_i
    {
        int r = tid >> 5, i = tid & 31;
        const float4* u4 = (const float4*)&Ut_ws[(b * NT + i) * Dd];
        float s = 0.f;
        #pragma unroll 4
        for (int kk = 0; kk < 48; kk++) s += dot4(u4[kk], ((float4*)XS[r])[kk]);
        float coef = (i <= n) ? memcoef(n, i) : 0.f;
        WQ[tid] = s * coef;
    }
    __syncthreads();

    // x4 = x3 + 0.5 * sum_i WQ * err_i   (err streamed coalesced from global)
    if (tid < Dd) {
        float acc[RTT] = {};
        for (int i = 0; i < NT; i++) {
            float e = Et_ws[(b * NT + i) * Dd + tid];
            #pragma unroll
            for (int r = 0; r < RTT; r++) acc[r] += WQ[r * NT + i] * e;
        }
        #pragma unroll
        for (int r = 0; r < RTT; r++) XS[r][tid] += 0.5f * acc[r];
    }
    __syncthreads();

    // LN2 stats
    {
        int r = tid >> 5, j = tid & 31;
        float s = 0.f, sq = 0.f;
        for (int d = j; d < Dd; d += 32) { float v = XS[r][d]; s += v; sq += v * v; }
        for (int off = 16; off > 0; off >>= 1) {
            s += __shfl_down(s, off, 32); sq += __shfl_down(sq, off, 32);
        }
        if (j == 0) {
            float mean = s / Dd;
            mv[r][0] = mean;
            mv[r][1] = rsqrtf(sq / Dd - mean * mean + EPSc);
        }
    }
    __syncthreads();

    if (tid < Dd) {
        float g = ln2_g[tid], bb = ln2_b[tid];
        float sum = 0.f;
        #pragma unroll
        for (int r = 0; r < RTT; r++)
            sum += (XS[r][tid] - mv[r][0]) * mv[r][1] * g + bb;
        atomicAdd(&pooled[b * Dd + tid], sum);
    }
}

// ---------------------------------------------------------------------------
__global__ __launch_bounds__(192) void head(
    const float* __restrict__ pooled, const float* __restrict__ Wc,
    const float* __restrict__ bc, float* __restrict__ out)
{
    int tid = threadIdx.x;
    if (tid < Bb * NCc) {
        int b = tid / NCc, c = tid - b * NCc;
        float s = 0.f;
        for (int d = 0; d < Dd; d++) s += pooled[b * Dd + d] * Wc[d * NCc + c];
        out[tid] = s * (1.0f / Tt) + bc[c];
    }
}

extern "C" void kernel_launch(void* const* d_in, const int* in_sizes, int n_in,
                              void* d_out, int out_size, void* d_ws, size_t ws_size,
                              hipStream_t stream) {
    const float* x     = (const float*)d_in[0];
    const float* W_in  = (const float*)d_in[1];
    const float* b_in  = (const float*)d_in[2];
    const float* Wv_a  = (const float*)d_in[3];
    const float* bv_a  = (const float*)d_in[4];
    const float* Wo_a  = (const float*)d_in[5];
    const float* bo_a  = (const float*)d_in[6];
    const float* ln1_g = (const float*)d_in[7];
    const float* ln1_b = (const float*)d_in[8];
    const float* pw1_w = (const float*)d_in[9];
    const float* pw1_b = (const float*)d_in[10];
    const float* dw_w  = (const float*)d_in[11];
    const float* dw_b  = (const float*)d_in[12];
    const float* bn_s  = (const float*)d_in[13];
    const float* bn_b  = (const float*)d_in[14];
    const float* pw2_w = (const float*)d_in[15];
    const float* pw2_b = (const float*)d_in[16];
    const float* Wk_t  = (const float*)d_in[17];
    const float* Wv_t  = (const float*)d_in[18];
    const float* Wq_t  = (const float*)d_in[19];
    const float* Wk_d  = (const float*)d_in[20];
    const float* Wv_d  = (const float*)d_in[21];
    const float* Wq_d  = (const float*)d_in[22];
    const float* ln2_g = (const float*)d_in[23];
    const float* ln2_b = (const float*)d_in[24];
    const float* Wc    = (const float*)d_in[25];
    const float* bc    = (const float*)d_in[26];

    float* ws = (float*)d_ws;
    size_t off = 0;
    float* x3_ws  = ws + off; off += (size_t)Bb * Tt * Dd;
    float* Ed_ws  = ws + off; off += Bb * ND * Dd;
    float* Ud_ws  = ws + off; off += Bb * ND * Dd;
    float* Kt_ws  = ws + off; off += Bb * NT * Dd;
    float* Et_ws  = ws + off; off += Bb * NT * Dd;
    float* Ut_ws  = ws + off; off += Bb * NT * Dd;
    float* pooled = ws + off; off += Bb * Dd;
    float* WinT   = ws + off; off += Dd * MEL;
    float* pw1aT  = ws + off; off += Dd * Dd;
    float* pw1gT  = ws + off; off += Dd * Dd;
    float* pw2T   = ws + off; off += Dd * Dd;
    float* WktT   = ws + off; off += Dd * Dd;
    float* WvtT   = ws + off; off += Dd * Dd;
    float* WavoT  = ws + off; off += Dd * Dd;
    float* b_avo  = ws + off; off += Dd;

    hipMemsetAsync(pooled, 0, Bb * Dd * sizeof(float), stream);

    prep<<<425, 192, 0, stream>>>(
        W_in, pw1_w, pw2_w, Wk_t, Wv_t, Wv_a, Wo_a, bv_a, bo_a,
        x, b_in, Wk_d, Wv_d, Wq_d,
        WinT, pw1aT, pw1gT, pw2T, WktT, WvtT, WavoT, b_avo, Ed_ws, Ud_ws);
    pipeline<<<Bb * PTILES, 192, 0, stream>>>(
        x, b_in, ln1_g, ln1_b, pw1_b, dw_w, dw_b, bn_s, bn_b, pw2_b,
        WinT, WavoT, b_avo, pw1aT, pw1gT, pw2T, WktT, WvtT,
        Ed_ws, Ud_ws, x3_ws, Kt_ws, Et_ws);
    theta_solve<<<Bb * 5, 192, 0, stream>>>(Wq_t, Kt_ws, Et_ws, Ut_ws);
    retrieve<<<Bb * RTILES, 256, 0, stream>>>(
        x3_ws, Ut_ws, Et_ws, ln2_g, ln2_b, pooled);
    head<<<1, 192, 0, stream>>>(pooled, Wc, bc, (float*)d_out);
}

// Round 4
// 240.500 us; speedup vs baseline: 1.3395x; 1.3395x over previous
//
#include <hip/hip_runtime.h>
#include <math.h>

#define Bb 8
#define Tt 256
#define MEL 128
#define Dd 192
#define NCc 20
#define ND 4                  // delta ranks (updates at t%64==0)
#define NT 32                 // theta ranks (updates at t%8==0)
#define ETAc 0.9f
#define LRc 0.1f
#define MDEC 0.99f            // 1 - ALPHA
#define EPSc 1e-5f
#define PT 4                  // pipeline rows per block
#define PTILES 64             // Tt/PT
#define RTT 8                 // retrieve rows per block
#define PADD 196              // padded LDS row (196%4==0, 196%32==4 -> <=4-way)

__device__ __forceinline__ float sigmoidf_(float x) {
    return 1.0f / (1.0f + __expf(-x));
}

// coefficient of (k_i err_i^T) in M_n, valid for i<=n
__device__ __forceinline__ float memcoef(int n, int i) {
    float m = LRc, pw = LRc;
    for (int nn = i + 1; nn <= n; nn++) { pw *= ETAc; m = MDEC * m + pw; }
    return m;
}

__device__ __forceinline__ float dot4(float4 a, float4 b) {
    return a.x * b.x + a.y * b.y + a.z * b.z + a.w * b.w;
}

// ---------------------------------------------------------------------------
// prep: grid 81 x 192.
//  [0,24)  Wavo = Wv_a @ Wo_a, 8 rows each (k-outer, coalesced)
//  [24]    b_avo = bv_a @ Wo_a + bo_a
//  [25,73) WqtT transpose (4 rows each)
//  [73,81) delta memory chain per batch
// ---------------------------------------------------------------------------
__global__ __launch_bounds__(192) void prep(
    const float* __restrict__ Wv_a, const float* __restrict__ Wo_a,
    const float* __restrict__ bv_a, const float* __restrict__ bo_a,
    const float* __restrict__ Wq_t,
    const float* __restrict__ x, const float* __restrict__ W_in,
    const float* __restrict__ b_in, const float* __restrict__ Wk_d,
    const float* __restrict__ Wv_d, const float* __restrict__ Wq_d,
    float* __restrict__ Wavo_ws, float* __restrict__ b_avo,
    float* __restrict__ WqtT,
    float* __restrict__ Ed_ws, float* __restrict__ Ud_ws)
{
    __shared__ __align__(16) float smem[2848];
    int blk = blockIdx.x, tid = threadIdx.x;

    if (blk < 24) {                               // Wavo rows m0..m0+7
        int m0 = 8 * blk;
        float* WVA = smem;                        // [8][192]
        for (int q = tid; q < 8 * 48; q += 192) {
            int r = q / 48, c = q - r * 48;
            ((float4*)(WVA + r * Dd))[c] = ((const float4*)&Wv_a[(m0 + r) * Dd])[c];
        }
        __syncthreads();
        int o = tid;
        float acc[8] = {};
        #pragma unroll 8
        for (int k = 0; k < Dd; k += 4) {
            float w0 = Wo_a[(k + 0) * Dd + o], w1 = Wo_a[(k + 1) * Dd + o];
            float w2 = Wo_a[(k + 2) * Dd + o], w3 = Wo_a[(k + 3) * Dd + o];
            #pragma unroll
            for (int r = 0; r < 8; r++) {
                float4 xv = *(const float4*)(WVA + r * Dd + k);
                acc[r] += w0 * xv.x + w1 * xv.y + w2 * xv.z + w3 * xv.w;
            }
        }
        #pragma unroll
        for (int r = 0; r < 8; r++) Wavo_ws[(m0 + r) * Dd + o] = acc[r];
        return;
    }
    if (blk == 24) {                              // b_avo
        int o = tid;
        float s = bo_a[o];
        #pragma unroll 4
        for (int m = 0; m < Dd; m++) s += bv_a[m] * Wo_a[m * Dd + o];
        b_avo[o] = s;
        return;
    }
    if (blk < 73) {                               // WqtT[e][o] = Wq_t[o][e]
        int r0 = 4 * (blk - 25);
        float4 v;
        v.x = Wq_t[(r0 + 0) * Dd + tid];
        v.y = Wq_t[(r0 + 1) * Dd + tid];
        v.z = Wq_t[(r0 + 2) * Dd + tid];
        v.w = Wq_t[(r0 + 3) * Dd + tid];
        *(float4*)&WqtT[tid * Dd + r0] = v;
        return;
    }

    // ---- delta chain for batch b ----
    int b = blk - 73;
    float* XR4 = smem;             // [4][128]
    float* XP4 = smem + 512;       // [4][192]
    float* K4  = XP4 + 4 * Dd;     // [4][192]
    float* V4  = K4 + 4 * Dd;      // [4][192]  (err after recurrence)
    float* G   = V4 + 4 * Dd;      // [16]
    float* mc  = G + 16;           // [16]

    if (tid < 128) {
        int i = tid >> 5, c = tid & 31;
        ((float4*)(XR4 + i * MEL))[c] =
            ((const float4*)&x[((size_t)b * Tt + 64 * i) * MEL])[c];
    }
    __syncthreads();
    {                                             // xp = x @ W_in + b_in
        float a0 = b_in[tid], a1 = a0, a2 = a0, a3 = a0;
        #pragma unroll 4
        for (int d = 0; d < MEL; d++) {
            float w = W_in[d * Dd + tid];
            a0 += XR4[d] * w;            a1 += XR4[MEL + d] * w;
            a2 += XR4[2 * MEL + d] * w;  a3 += XR4[3 * MEL + d] * w;
        }
        XP4[tid] = a0; XP4[Dd + tid] = a1; XP4[2 * Dd + tid] = a2; XP4[3 * Dd + tid] = a3;
    }
    __syncthreads();
    {                                             // k,v projections
        float k0 = 0, k1 = 0, k2 = 0, k3 = 0, v0 = 0, v1 = 0, v2 = 0, v3 = 0;
        #pragma unroll 4
        for (int d = 0; d < Dd; d++) {
            float wk = Wk_d[d * Dd + tid], wv = Wv_d[d * Dd + tid];
            float x0 = XP4[d], x1 = XP4[Dd + d], x2 = XP4[2 * Dd + d], x3 = XP4[3 * Dd + d];
            k0 += x0 * wk; k1 += x1 * wk; k2 += x2 * wk; k3 += x3 * wk;
            v0 += x0 * wv; v1 += x1 * wv; v2 += x2 * wv; v3 += x3 * wv;
        }
        K4[tid] = k0; K4[Dd + tid] = k1; K4[2 * Dd + tid] = k2; K4[3 * Dd + tid] = k3;
        V4[tid] = v0; V4[Dd + tid] = v1; V4[2 * Dd + tid] = v2; V4[3 * Dd + tid] = v3;
    }
    __syncthreads();
    if (tid < 16) {                               // Gram + coefficient table
        int i = tid >> 2, j = tid & 3;
        float s = 0.f;
        for (int d = 0; d < Dd; d++) s += K4[i * Dd + d] * K4[j * Dd + d];
        G[tid] = s;
        mc[tid] = (j <= i) ? memcoef(i, j) : 0.f;  // mc[n=i][i=j]
    }
    __syncthreads();
    for (int i = 1; i < ND; i++) {                // err recurrence
        float acc = V4[i * Dd + tid];
        for (int m = 0; m < i; m++)
            acc -= mc[(i - 1) * ND + m] * G[i * ND + m] * V4[m * Dd + tid];
        __syncthreads();
        V4[i * Dd + tid] = acc;
        __syncthreads();
    }
    {                                             // u_i = Wq_d @ k_i ; store err,u
        float u0 = 0, u1 = 0, u2 = 0, u3 = 0;
        const float4* row4 = (const float4*)&Wq_d[tid * Dd];
        #pragma unroll 4
        for (int kk = 0; kk < 48; kk++) {
            float4 w = row4[kk];
            u0 += dot4(w, ((float4*)K4)[kk]);
            u1 += dot4(w, ((float4*)(K4 + Dd))[kk]);
            u2 += dot4(w, ((float4*)(K4 + 2 * Dd))[kk]);
            u3 += dot4(w, ((float4*)(K4 + 3 * Dd))[kk]);
        }
        Ud_ws[(b * ND + 0) * Dd + tid] = u0;
        Ud_ws[(b * ND + 1) * Dd + tid] = u1;
        Ud_ws[(b * ND + 2) * Dd + tid] = u2;
        Ud_ws[(b * ND + 3) * Dd + tid] = u3;
        for (int i = 0; i < ND; i++) Ed_ws[(b * ND + i) * Dd + tid] = V4[i * Dd + tid];
    }
}

// ---------------------------------------------------------------------------
// pipeline: grid B*64 (4 rows/block), 192 threads. k-outer coalesced weight
// loads in ORIGINAL layouts. Produces x3 only.
// ---------------------------------------------------------------------------
__global__ __launch_bounds__(192) void pipeline(
    const float* __restrict__ x, const float* __restrict__ W_in,
    const float* __restrict__ b_in,
    const float* __restrict__ ln1_g, const float* __restrict__ ln1_b,
    const float* __restrict__ pw1_w, const float* __restrict__ pw1_b,
    const float* __restrict__ dw_w, const float* __restrict__ dw_b,
    const float* __restrict__ bn_s, const float* __restrict__ bn_b,
    const float* __restrict__ pw2_w, const float* __restrict__ pw2_b,
    const float* __restrict__ Wavo_ws, const float* __restrict__ b_avo,
    const float* __restrict__ Ed_ws, const float* __restrict__ Ud_ws,
    float* __restrict__ x3_ws)
{
    int blk = blockIdx.x;
    int b = blk >> 6, tile = blk & 63;
    int t0 = tile * PT, n = tile >> 4;     // delta epoch, tile-uniform
    int tid = threadIdx.x;

    __shared__ __align__(16) float XR[PT][MEL];
    __shared__ __align__(16) float XP[PT][Dd];
    __shared__ __align__(16) float ED[ND][PADD], UD[ND][PADD];
    __shared__ __align__(16) float X1[PT][Dd], X2[PT][Dd];
    __shared__ __align__(16) float LNX[PT][Dd], HG[PT][Dd];
    __shared__ float WQs[PT * ND];
    __shared__ float mv[PT][2];

    if (tid < 128) {
        int r = tid >> 5, c = tid & 31;
        ((float4*)XR[r])[c] = ((const float4*)&x[((size_t)b * Tt + t0 + r) * MEL])[c];
    }
    for (int q = tid; q < ND * 48 * 2; q += 192) {
        int which = q >= ND * 48;
        int qq = which ? q - ND * 48 : q;
        int i = qq / 48, c = qq - i * 48;
        if (!which) ((float4*)ED[i])[c] = ((const float4*)&Ed_ws[(b * ND + i) * Dd])[c];
        else        ((float4*)UD[i])[c] = ((const float4*)&Ud_ws[(b * ND + i) * Dd])[c];
    }
    __syncthreads();

    int o = tid;
    // xp = x @ W_in + b_in   (K=128)
    {
        float acc[PT];
        float bb = b_in[o];
        #pragma unroll
        for (int r = 0; r < PT; r++) acc[r] = bb;
        #pragma unroll 8
        for (int k = 0; k < MEL; k += 4) {
            float w0 = W_in[(k + 0) * Dd + o], w1 = W_in[(k + 1) * Dd + o];
            float w2 = W_in[(k + 2) * Dd + o], w3 = W_in[(k + 3) * Dd + o];
            #pragma unroll
            for (int r = 0; r < PT; r++) {
                float4 xv = *(const float4*)&XR[r][k];
                acc[r] += w0 * xv.x + w1 * xv.y + w2 * xv.z + w3 * xv.w;
            }
        }
        #pragma unroll
        for (int r = 0; r < PT; r++) XP[r][tid] = acc[r];
    }
    __syncthreads();

    // delta dots: WQs[r][i] = (xp_r . u_i) * coef(n,i)
    if (tid < 128) {
        int r = tid >> 5, i = (tid >> 3) & 3, c = tid & 7;
        float s = 0.f;
        const float* xp = XP[r];
        const float* u = UD[i];
        #pragma unroll
        for (int j = 0; j < 24; j++) s += xp[c * 24 + j] * u[c * 24 + j];
        s += __shfl_down(s, 4, 8);
        s += __shfl_down(s, 2, 8);
        s += __shfl_down(s, 1, 8);
        if (c == 0) {
            float coef = (i <= n) ? memcoef(n, i) : 0.f;
            WQs[r * ND + i] = s * coef;
        }
    }
    __syncthreads();

    // x1 = xp + 0.5 * sum_i WQs * err_i
    {
        #pragma unroll
        for (int r = 0; r < PT; r++) {
            float dout = WQs[r * ND + 0] * ED[0][tid] + WQs[r * ND + 1] * ED[1][tid]
                       + WQs[r * ND + 2] * ED[2][tid] + WQs[r * ND + 3] * ED[3][tid];
            X1[r][tid] = XP[r][tid] + 0.5f * dout;
        }
    }
    __syncthreads();

    // x2 = x1 + x1 @ Wavo + b_avo   (K=192)
    {
        float acc[PT];
        float bb = b_avo[o];
        #pragma unroll
        for (int r = 0; r < PT; r++) acc[r] = bb;
        #pragma unroll 8
        for (int k = 0; k < Dd; k += 4) {
            float w0 = Wavo_ws[(k + 0) * Dd + o], w1 = Wavo_ws[(k + 1) * Dd + o];
            float w2 = Wavo_ws[(k + 2) * Dd + o], w3 = Wavo_ws[(k + 3) * Dd + o];
            #pragma unroll
            for (int r = 0; r < PT; r++) {
                float4 xv = *(const float4*)&X1[r][k];
                acc[r] += w0 * xv.x + w1 * xv.y + w2 * xv.z + w3 * xv.w;
            }
        }
        #pragma unroll
        for (int r = 0; r < PT; r++) X2[r][tid] = X1[r][tid] + acc[r];
    }
    __syncthreads();

    // LN1 stats (4 groups of 32 lanes)
    if (tid < 128) {
        int r = tid >> 5, j = tid & 31;
        float s = 0.f, sq = 0.f;
        for (int d = j; d < Dd; d += 32) { float v = X2[r][d]; s += v; sq += v * v; }
        for (int off = 16; off > 0; off >>= 1) {
            s += __shfl_down(s, off, 32); sq += __shfl_down(sq, off, 32);
        }
        if (j == 0) {
            float mean = s / Dd;
            mv[r][0] = mean;
            mv[r][1] = rsqrtf(sq / Dd - mean * mean + EPSc);
        }
    }
    __syncthreads();
    {
        float g = ln1_g[tid], bb = ln1_b[tid];
        #pragma unroll
        for (int r = 0; r < PT; r++)
            LNX[r][tid] = (X2[r][tid] - mv[r][0]) * mv[r][1] * g + bb;
    }
    __syncthreads();

    // pw1 (dual halves) + GLU + dw + bn + silu   (K=192, 2 outputs)
    {
        float aa[PT], gg[PT];
        float ba = pw1_b[o], bg = pw1_b[o + Dd];
        #pragma unroll
        for (int r = 0; r < PT; r++) { aa[r] = ba; gg[r] = bg; }
        #pragma unroll 4
        for (int k = 0; k < Dd; k += 4) {
            float wa0 = pw1_w[(k + 0) * 2 * Dd + o], wg0 = pw1_w[(k + 0) * 2 * Dd + Dd + o];
            float wa1 = pw1_w[(k + 1) * 2 * Dd + o], wg1 = pw1_w[(k + 1) * 2 * Dd + Dd + o];
            float wa2 = pw1_w[(k + 2) * 2 * Dd + o], wg2 = pw1_w[(k + 2) * 2 * Dd + Dd + o];
            float wa3 = pw1_w[(k + 3) * 2 * Dd + o], wg3 = pw1_w[(k + 3) * 2 * Dd + Dd + o];
            #pragma unroll
            for (int r = 0; r < PT; r++) {
                float4 xv = *(const float4*)&LNX[r][k];
                aa[r] += wa0 * xv.x + wa1 * xv.y + wa2 * xv.z + wa3 * xv.w;
                gg[r] += wg0 * xv.x + wg1 * xv.y + wg2 * xv.z + wg3 * xv.w;
            }
        }
        float dww = dw_w[o], dwb = dw_b[o], bns = bn_s[o], bnb = bn_b[o];
        #pragma unroll
        for (int r = 0; r < PT; r++) {
            float h = aa[r] * sigmoidf_(gg[r]);
            h = h * dww + dwb;
            h = h * bns + bnb;
            h = h * sigmoidf_(h);
            HG[r][tid] = h;
        }
    }
    __syncthreads();

    // pw2 + residual -> x3 (direct store)
    {
        float acc[PT];
        float bb = pw2_b[o];
        #pragma unroll
        for (int r = 0; r < PT; r++) acc[r] = bb;
        #pragma unroll 8
        for (int k = 0; k < Dd; k += 4) {
            float w0 = pw2_w[(k + 0) * Dd + o], w1 = pw2_w[(k + 1) * Dd + o];
            float w2 = pw2_w[(k + 2) * Dd + o], w3 = pw2_w[(k + 3) * Dd + o];
            #pragma unroll
            for (int r = 0; r < PT; r++) {
                float4 xv = *(const float4*)&HG[r][k];
                acc[r] += w0 * xv.x + w1 * xv.y + w2 * xv.z + w3 * xv.w;
            }
        }
        #pragma unroll
        for (int r = 0; r < PT; r++)
            x3_ws[((size_t)b * Tt + t0 + r) * Dd + tid] = X2[r][tid] + acc[r];
    }
}

// ---------------------------------------------------------------------------
// theta_proj: grid B*4 (8 update rows each). k/v = x3[t=8i] @ Wk_t/Wv_t,
// k-outer coalesced, original layout.
// ---------------------------------------------------------------------------
__global__ __launch_bounds__(192) void theta_proj(
    const float* __restrict__ x3_ws,
    const float* __restrict__ Wk_t, const float* __restrict__ Wv_t,
    float* __restrict__ Kt_ws, float* __restrict__ Et_ws)
{
    int blk = blockIdx.x, b = blk >> 2, g = blk & 3;
    int tid = threadIdx.x;
    __shared__ __align__(16) float XS[8][Dd];

    for (int q = tid; q < 8 * 48; q += 192) {
        int r = q / 48, c = q - r * 48;
        ((float4*)XS[r])[c] =
            ((const float4*)&x3_ws[((size_t)b * Tt + 64 * g + 8 * r) * Dd])[c];
    }
    __syncthreads();

    int o = tid;
    float ak[8] = {}, av[8] = {};
    #pragma unroll 4
    for (int k = 0; k < Dd; k += 4) {
        float k0 = Wk_t[(k + 0) * Dd + o], k1 = Wk_t[(k + 1) * Dd + o];
        float k2 = Wk_t[(k + 2) * Dd + o], k3 = Wk_t[(k + 3) * Dd + o];
        float v0 = Wv_t[(k + 0) * Dd + o], v1 = Wv_t[(k + 1) * Dd + o];
        float v2 = Wv_t[(k + 2) * Dd + o], v3 = Wv_t[(k + 3) * Dd + o];
        #pragma unroll
        for (int r = 0; r < 8; r++) {
            float4 xv = *(const float4*)&XS[r][k];
            ak[r] += k0 * xv.x + k1 * xv.y + k2 * xv.z + k3 * xv.w;
            av[r] += v0 * xv.x + v1 * xv.y + v2 * xv.z + v3 * xv.w;
        }
    }
    #pragma unroll
    for (int r = 0; r < 8; r++) {
        int i = 8 * g + r;
        Kt_ws[(b * NT + i) * Dd + o] = ak[r];
        Et_ws[(b * NT + i) * Dd + o] = av[r];
    }
}

// ---------------------------------------------------------------------------
// theta_solve: grid B*5. role 0: Gram + 31-step err recurrence (rewrites Et).
// roles 1..4: u~_i = Wq_t @ k_i via WqtT (k-outer coalesced), 8 i's each.
// ---------------------------------------------------------------------------
__global__ __launch_bounds__(192) void theta_solve(
    const float* __restrict__ WqtT, const float* __restrict__ Kt_ws,
    float* __restrict__ Et_ws, float* __restrict__ Ut_ws)
{
    int blk = blockIdx.x, b = blk / 5, role = blk % 5, tid = threadIdx.x;
    if (role == 0) {
        __shared__ __align__(16) float K[NT][PADD], E[NT][PADD];
        __shared__ float G[NT * NT], mc[NT * NT];
        for (int q = tid; q < NT * 48; q += 192) {
            int i = q / 48, c = q - i * 48;
            ((float4*)K[i])[c] = ((const float4*)&Kt_ws[(b * NT + i) * Dd])[c];
            ((float4*)E[i])[c] = ((const float4*)&Et_ws[(b * NT + i) * Dd])[c];
        }
        if (tid < NT) {
            int i = tid;
            float m = 0.f, pw = LRc;
            for (int nn = 0; nn < NT; nn++) {
                float v;
                if (nn < i) v = 0.f;
                else if (nn == i) { m = LRc; v = m; }
                else { pw *= ETAc; m = MDEC * m + pw; v = m; }
                mc[nn * NT + i] = v;
            }
        }
        __syncthreads();
        for (int p = tid; p < NT * NT; p += 192) {
            int i = p >> 5, j = p & 31;
            const float4* ki = (const float4*)K[i];
            const float4* kj = (const float4*)K[j];
            float s = 0.f;
            #pragma unroll 4
            for (int kk = 0; kk < 48; kk++) s += dot4(ki[kk], kj[kk]);
            G[p] = s;
        }
        __syncthreads();
        for (int i = 1; i < NT; i++) {
            float acc = E[i][tid];
            for (int m = 0; m < i; m++)
                acc -= mc[(i - 1) * NT + m] * G[i * NT + m] * E[m][tid];
            __syncthreads();
            E[i][tid] = acc;
            __syncthreads();
        }
        for (int i = 0; i < NT; i++) Et_ws[(b * NT + i) * Dd + tid] = E[i][tid];
    } else {
        __shared__ __align__(16) float K8[8][Dd];
        int i0 = (role - 1) * 8;
        for (int q = tid; q < 8 * 48; q += 192) {
            int i = q / 48, c = q - i * 48;
            ((float4*)K8[i])[c] = ((const float4*)&Kt_ws[(b * NT + i0 + i) * Dd])[c];
        }
        __syncthreads();
        int o = tid;
        float acc[8] = {};
        #pragma unroll 8
        for (int k = 0; k < Dd; k += 4) {
            float w0 = WqtT[(k + 0) * Dd + o], w1 = WqtT[(k + 1) * Dd + o];
            float w2 = WqtT[(k + 2) * Dd + o], w3 = WqtT[(k + 3) * Dd + o];
            #pragma unroll
            for (int i = 0; i < 8; i++) {
                float4 kv = *(const float4*)&K8[i][k];
                acc[i] += w0 * kv.x + w1 * kv.y + w2 * kv.z + w3 * kv.w;
            }
        }
        #pragma unroll
        for (int i = 0; i < 8; i++) Ut_ws[(b * NT + i0 + i) * Dd + o] = acc[i];
    }
}

// ---------------------------------------------------------------------------
// retrieve: grid B*32 (8 rows/block), 256 threads. Ut/x3 staged in padded LDS
// (coalesced loads), dots + rank-32 combine + LN2 + pooled accumulation.
// ---------------------------------------------------------------------------
__global__ __launch_bounds__(256) void retrieve(
    const float* __restrict__ x3_ws, const float* __restrict__ Ut_ws,
    const float* __restrict__ Et_ws, const float* __restrict__ ln2_g,
    const float* __restrict__ ln2_b, float* __restrict__ pooled)
{
    int blk = blockIdx.x, b = blk >> 5, tile = blk & 31;
    int t0 = tile * RTT, n = tile;
    int tid = threadIdx.x;

    __shared__ __align__(16) float UT[NT][PADD];
    __shared__ __align__(16) float XS[RTT][PADD];
    __shared__ float WQ[RTT * NT];
    __shared__ float mv[RTT][2];

    for (int q = tid; q < NT * 48; q += 256) {
        int i = q / 48, c = q - i * 48;
        ((float4*)UT[i])[c] = ((const float4*)&Ut_ws[(b * NT + i) * Dd])[c];
    }
    for (int q = tid; q < RTT * 48; q += 256) {
        int r = q / 48, c = q - r * 48;
        ((float4*)XS[r])[c] = ((const float4*)&x3_ws[((size_t)b * Tt + t0 + r) * Dd])[c];
    }
    __syncthreads();

    // dots: tid = r*32 + i ; w[r][i] = (x3_r . u~_i) * coef
    {
        int r = tid >> 5, i = tid & 31;
        const float4* u4 = (const float4*)UT[i];
        const float4* x4 = (const float4*)XS[r];
        float s = 0.f;
        #pragma unroll 8
        for (int kk = 0; kk < 48; kk++) s += dot4(u4[kk], x4[kk]);
        float coef = (i <= n) ? memcoef(n, i) : 0.f;
        WQ[tid] = s * coef;
    }
    __syncthreads();

    // x4 = x3 + 0.5 * sum_i WQ * err_i   (err streamed coalesced from global)
    if (tid < Dd) {
        float acc[RTT] = {};
        #pragma unroll 4
        for (int i = 0; i < NT; i++) {
            float e = Et_ws[(b * NT + i) * Dd + tid];
            #pragma unroll
            for (int r = 0; r < RTT; r++) acc[r] += WQ[r * NT + i] * e;
        }
        #pragma unroll
        for (int r = 0; r < RTT; r++) XS[r][tid] += 0.5f * acc[r];
    }
    __syncthreads();

    // LN2 stats
    {
        int r = tid >> 5, j = tid & 31;
        float s = 0.f, sq = 0.f;
        for (int d = j; d < Dd; d += 32) { float v = XS[r][d]; s += v; sq += v * v; }
        for (int off = 16; off > 0; off >>= 1) {
            s += __shfl_down(s, off, 32); sq += __shfl_down(sq, off, 32);
        }
        if (j == 0) {
            float mean = s / Dd;
            mv[r][0] = mean;
            mv[r][1] = rsqrtf(sq / Dd - mean * mean + EPSc);
        }
    }
    __syncthreads();

    if (tid < Dd) {
        float g = ln2_g[tid], bb = ln2_b[tid];
        float sum = 0.f;
        #pragma unroll
        for (int r = 0; r < RTT; r++)
            sum += (XS[r][tid] - mv[r][0]) * mv[r][1] * g + bb;
        atomicAdd(&pooled[b * Dd + tid], sum);
    }
}

// ---------------------------------------------------------------------------
__global__ __launch_bounds__(192) void head(
    const float* __restrict__ pooled, const float* __restrict__ Wc,
    const float* __restrict__ bc, float* __restrict__ out)
{
    int tid = threadIdx.x;
    if (tid < Bb * NCc) {
        int b = tid / NCc, c = tid - b * NCc;
        float s = 0.f;
        for (int d = 0; d < Dd; d++) s += pooled[b * Dd + d] * Wc[d * NCc + c];
        out[tid] = s * (1.0f / Tt) + bc[c];
    }
}

extern "C" void kernel_launch(void* const* d_in, const int* in_sizes, int n_in,
                              void* d_out, int out_size, void* d_ws, size_t ws_size,
                              hipStream_t stream) {
    const float* x     = (const float*)d_in[0];
    const float* W_in  = (const float*)d_in[1];
    const float* b_in  = (const float*)d_in[2];
    const float* Wv_a  = (const float*)d_in[3];
    const float* bv_a  = (const float*)d_in[4];
    const float* Wo_a  = (const float*)d_in[5];
    const float* bo_a  = (const float*)d_in[6];
    const float* ln1_g = (const float*)d_in[7];
    const float* ln1_b = (const float*)d_in[8];
    const float* pw1_w = (const float*)d_in[9];
    const float* pw1_b = (const float*)d_in[10];
    const float* dw_w  = (const float*)d_in[11];
    const float* dw_b  = (const float*)d_in[12];
    const float* bn_s  = (const float*)d_in[13];
    const float* bn_b  = (const float*)d_in[14];
    const float* pw2_w = (const float*)d_in[15];
    const float* pw2_b = (const float*)d_in[16];
    const float* Wk_t  = (const float*)d_in[17];
    const float* Wv_t  = (const float*)d_in[18];
    const float* Wq_t  = (const float*)d_in[19];
    const float* Wk_d  = (const float*)d_in[20];
    const float* Wv_d  = (const float*)d_in[21];
    const float* Wq_d  = (const float*)d_in[22];
    const float* ln2_g = (const float*)d_in[23];
    const float* ln2_b = (const float*)d_in[24];
    const float* Wc    = (const float*)d_in[25];
    const float* bc    = (const float*)d_in[26];

    float* ws = (float*)d_ws;
    size_t off = 0;
    float* x3_ws   = ws + off; off += (size_t)Bb * Tt * Dd;
    float* Ed_ws   = ws + off; off += Bb * ND * Dd;
    float* Ud_ws   = ws + off; off += Bb * ND * Dd;
    float* Kt_ws   = ws + off; off += Bb * NT * Dd;
    float* Et_ws   = ws + off; off += Bb * NT * Dd;
    float* Ut_ws   = ws + off; off += Bb * NT * Dd;
    float* pooled  = ws + off; off += Bb * Dd;
    float* Wavo_ws = ws + off; off += Dd * Dd;
    float* WqtT    = ws + off; off += Dd * Dd;
    float* b_avo   = ws + off; off += Dd;

    hipMemsetAsync(pooled, 0, Bb * Dd * sizeof(float), stream);

    prep<<<81, 192, 0, stream>>>(
        Wv_a, Wo_a, bv_a, bo_a, Wq_t,
        x, W_in, b_in, Wk_d, Wv_d, Wq_d,
        Wavo_ws, b_avo, WqtT, Ed_ws, Ud_ws);
    pipeline<<<Bb * PTILES, 192, 0, stream>>>(
        x, W_in, b_in, ln1_g, ln1_b, pw1_w, pw1_b, dw_w, dw_b,
        bn_s, bn_b, pw2_w, pw2_b, Wavo_ws, b_avo, Ed_ws, Ud_ws, x3_ws);
    theta_proj<<<Bb * 4, 192, 0, stream>>>(x3_ws, Wk_t, Wv_t, Kt_ws, Et_ws);
    theta_solve<<<Bb * 5, 192, 0, stream>>>(WqtT, Kt_ws, Et_ws, Ut_ws);
    retrieve<<<Bb * 32, 256, 0, stream>>>(
        x3_ws, Ut_ws, Et_ws, ln2_g, ln2_b, pooled);
    head<<<1, 192, 0, stream>>>(pooled, Wc, bc, (float*)d_out);
}

// Round 5
// 207.630 us; speedup vs baseline: 1.5515x; 1.1583x over previous
//
#include <hip/hip_runtime.h>
#include <math.h>

#define Bb 8
#define Tt 256
#define MEL 128
#define Dd 192
#define NCc 20
#define ND 4                  // delta ranks (updates at t%64==0)
#define NT 32                 // theta ranks (updates at t%8==0)
#define ETAc 0.9f
#define LRc 0.1f
#define MDEC 0.99f            // 1 - ALPHA
#define EPSc 1e-5f
#define PT 4                  // pipeline rows per block
#define PTILES 64             // Tt/PT
#define RTT 8                 // retrieve rows per block
#define PADD 196              // padded LDS row (196%4==0, 196%32==4 -> <=4-way)

__device__ __forceinline__ float sigmoidf_(float x) {
    return 1.0f / (1.0f + __expf(-x));
}

// coefficient of (k_i err_i^T) in M_n, valid for i<=n
__device__ __forceinline__ float memcoef(int n, int i) {
    float m = LRc, pw = LRc;
    for (int nn = i + 1; nn <= n; nn++) { pw *= ETAc; m = MDEC * m + pw; }
    return m;
}

__device__ __forceinline__ float dot4(float4 a, float4 b) {
    return a.x * b.x + a.y * b.y + a.z * b.z + a.w * b.w;
}

// ---------------------------------------------------------------------------
// prep: grid 322 x 192 — everything parallel & coalesced.
//  [0,192)   Wavo row m = Wv_a[m,:] @ Wo_a  (k-outer)
//  [192]     b_avo = bv_a @ Wo_a + bo_a
//  [193,241) WqtT transpose (4 rows each)
//  [241,289) WqdT transpose (4 rows each)
//  [289,321) delta k/v for (b,i): xp -> k,v   (32 blocks)
//  [321]     zero pooled
// ---------------------------------------------------------------------------
__global__ __launch_bounds__(192) void prep(
    const float* __restrict__ Wv_a, const float* __restrict__ Wo_a,
    const float* __restrict__ bv_a, const float* __restrict__ bo_a,
    const float* __restrict__ Wq_t, const float* __restrict__ Wq_d,
    const float* __restrict__ x, const float* __restrict__ W_in,
    const float* __restrict__ b_in, const float* __restrict__ Wk_d,
    const float* __restrict__ Wv_d,
    float* __restrict__ Wavo_ws, float* __restrict__ b_avo,
    float* __restrict__ WqtT, float* __restrict__ WqdT,
    float* __restrict__ Kd_ws, float* __restrict__ Vd_ws,
    float* __restrict__ pooled)
{
    __shared__ __align__(16) float smem[512];
    int blk = blockIdx.x, tid = threadIdx.x;

    if (blk < 192) {                              // Wavo row m (k-outer coalesced)
        int m = blk;
        smem[tid] = Wv_a[m * Dd + tid];
        __syncthreads();
        int o = tid;
        float acc = 0.f;
        #pragma unroll 8
        for (int k = 0; k < Dd; k += 4) {
            acc += Wo_a[(k + 0) * Dd + o] * smem[k + 0];
            acc += Wo_a[(k + 1) * Dd + o] * smem[k + 1];
            acc += Wo_a[(k + 2) * Dd + o] * smem[k + 2];
            acc += Wo_a[(k + 3) * Dd + o] * smem[k + 3];
        }
        Wavo_ws[m * Dd + o] = acc;
        return;
    }
    if (blk == 192) {                             // b_avo
        int o = tid;
        float s = bo_a[o];
        #pragma unroll 4
        for (int m = 0; m < Dd; m++) s += bv_a[m] * Wo_a[m * Dd + o];
        b_avo[o] = s;
        return;
    }
    if (blk < 241) {                              // WqtT[e][o] = Wq_t[o][e]
        int r0 = 4 * (blk - 193);
        float4 v;
        v.x = Wq_t[(r0 + 0) * Dd + tid];
        v.y = Wq_t[(r0 + 1) * Dd + tid];
        v.z = Wq_t[(r0 + 2) * Dd + tid];
        v.w = Wq_t[(r0 + 3) * Dd + tid];
        *(float4*)&WqtT[tid * Dd + r0] = v;
        return;
    }
    if (blk < 289) {                              // WqdT[e][o] = Wq_d[o][e]
        int r0 = 4 * (blk - 241);
        float4 v;
        v.x = Wq_d[(r0 + 0) * Dd + tid];
        v.y = Wq_d[(r0 + 1) * Dd + tid];
        v.z = Wq_d[(r0 + 2) * Dd + tid];
        v.w = Wq_d[(r0 + 3) * Dd + tid];
        *(float4*)&WqdT[tid * Dd + r0] = v;
        return;
    }
    if (blk == 321) {                             // zero pooled
        for (int q = tid; q < Bb * Dd; q += 192) pooled[q] = 0.f;
        return;
    }

    // ---- delta k/v for (b,i) ----
    int q = blk - 289;
    int b = q >> 2, i = q & 3;
    float* XR = smem;              // [128]
    float* XP = smem + 128;        // [192]
    if (tid < 128) XR[tid] = x[((size_t)b * Tt + 64 * i) * MEL + tid];
    __syncthreads();
    {
        int o = tid;
        float acc = b_in[o];
        #pragma unroll 8
        for (int k = 0; k < MEL; k += 4) {
            acc += W_in[(k + 0) * Dd + o] * XR[k + 0];
            acc += W_in[(k + 1) * Dd + o] * XR[k + 1];
            acc += W_in[(k + 2) * Dd + o] * XR[k + 2];
            acc += W_in[(k + 3) * Dd + o] * XR[k + 3];
        }
        XP[o] = acc;
    }
    __syncthreads();
    {
        int o = tid;
        float ak = 0.f, av = 0.f;
        #pragma unroll 4
        for (int k = 0; k < Dd; k += 4) {
            float x0 = XP[k + 0], x1 = XP[k + 1], x2 = XP[k + 2], x3 = XP[k + 3];
            ak += Wk_d[(k + 0) * Dd + o] * x0 + Wk_d[(k + 1) * Dd + o] * x1
                + Wk_d[(k + 2) * Dd + o] * x2 + Wk_d[(k + 3) * Dd + o] * x3;
            av += Wv_d[(k + 0) * Dd + o] * x0 + Wv_d[(k + 1) * Dd + o] * x1
                + Wv_d[(k + 2) * Dd + o] * x2 + Wv_d[(k + 3) * Dd + o] * x3;
        }
        Kd_ws[(b * ND + i) * Dd + o] = ak;
        Vd_ws[(b * ND + i) * Dd + o] = av;
    }
}

// ---------------------------------------------------------------------------
// delta_solve: grid B*5 = 40.
//  role 0: Gram 4x4 + 3-step err recurrence, rewrites Vd_ws in place (-> err)
//  roles 1..4: u_i = Wq_d @ k_i via WqdT (k-outer coalesced)
// ---------------------------------------------------------------------------
__global__ __launch_bounds__(192) void delta_solve(
    const float* __restrict__ WqdT, const float* __restrict__ Kd_ws,
    float* __restrict__ Vd_ws, float* __restrict__ Ud_ws)
{
    int blk = blockIdx.x, b = blk / 5, role = blk % 5, tid = threadIdx.x;
    if (role == 0) {
        __shared__ __align__(16) float K4[ND][Dd], V4[ND][Dd];
        __shared__ float G[16], mc[16];
        for (int q = tid; q < ND * 48; q += 192) {
            int i = q / 48, c = q - i * 48;
            ((float4*)K4[i])[c] = ((const float4*)&Kd_ws[(b * ND + i) * Dd])[c];
            ((float4*)V4[i])[c] = ((const float4*)&Vd_ws[(b * ND + i) * Dd])[c];
        }
        __syncthreads();
        if (tid < 16) {
            int i = tid >> 2, j = tid & 3;
            float s = 0.f;
            for (int d = 0; d < Dd; d++) s += K4[i][d] * K4[j][d];
            G[tid] = s;
            mc[tid] = (j <= i) ? memcoef(i, j) : 0.f;   // mc[n=i][i=j]
        }
        __syncthreads();
        for (int i = 1; i < ND; i++) {
            float acc = V4[i][tid];
            for (int m = 0; m < i; m++)
                acc -= mc[(i - 1) * ND + m] * G[i * ND + m] * V4[m][tid];
            V4[i][tid] = acc;        // writes row i; others read rows < i only
            __syncthreads();
        }
        for (int i = 0; i < ND; i++) Vd_ws[(b * ND + i) * Dd + tid] = V4[i][tid];
    } else {
        __shared__ float KS[Dd];
        int i = role - 1;
        KS[tid] = Kd_ws[(b * ND + i) * Dd + tid];
        __syncthreads();
        int o = tid;
        float acc = 0.f;
        #pragma unroll 8
        for (int k = 0; k < Dd; k += 4) {
            acc += WqdT[(k + 0) * Dd + o] * KS[k + 0];
            acc += WqdT[(k + 1) * Dd + o] * KS[k + 1];
            acc += WqdT[(k + 2) * Dd + o] * KS[k + 2];
            acc += WqdT[(k + 3) * Dd + o] * KS[k + 3];
        }
        Ud_ws[(b * ND + i) * Dd + o] = acc;
    }
}

// ---------------------------------------------------------------------------
// pipeline: grid B*64 (4 rows/block), 192 threads. k-outer coalesced weight
// loads in ORIGINAL layouts. Produces x3 only. (verified R4 body)
// ---------------------------------------------------------------------------
__global__ __launch_bounds__(192) void pipeline(
    const float* __restrict__ x, const float* __restrict__ W_in,
    const float* __restrict__ b_in,
    const float* __restrict__ ln1_g, const float* __restrict__ ln1_b,
    const float* __restrict__ pw1_w, const float* __restrict__ pw1_b,
    const float* __restrict__ dw_w, const float* __restrict__ dw_b,
    const float* __restrict__ bn_s, const float* __restrict__ bn_b,
    const float* __restrict__ pw2_w, const float* __restrict__ pw2_b,
    const float* __restrict__ Wavo_ws, const float* __restrict__ b_avo,
    const float* __restrict__ Ed_ws, const float* __restrict__ Ud_ws,
    float* __restrict__ x3_ws)
{
    int blk = blockIdx.x;
    int b = blk >> 6, tile = blk & 63;
    int t0 = tile * PT, n = tile >> 4;     // delta epoch, tile-uniform
    int tid = threadIdx.x;

    __shared__ __align__(16) float XR[PT][MEL];
    __shared__ __align__(16) float XP[PT][Dd];
    __shared__ __align__(16) float ED[ND][PADD], UD[ND][PADD];
    __shared__ __align__(16) float X1[PT][Dd], X2[PT][Dd];
    __shared__ __align__(16) float LNX[PT][Dd], HG[PT][Dd];
    __shared__ float WQs[PT * ND];
    __shared__ float mv[PT][2];

    if (tid < 128) {
        int r = tid >> 5, c = tid & 31;
        ((float4*)XR[r])[c] = ((const float4*)&x[((size_t)b * Tt + t0 + r) * MEL])[c];
    }
    for (int q = tid; q < ND * 48 * 2; q += 192) {
        int which = q >= ND * 48;
        int qq = which ? q - ND * 48 : q;
        int i = qq / 48, c = qq - i * 48;
        if (!which) ((float4*)ED[i])[c] = ((const float4*)&Ed_ws[(b * ND + i) * Dd])[c];
        else        ((float4*)UD[i])[c] = ((const float4*)&Ud_ws[(b * ND + i) * Dd])[c];
    }
    __syncthreads();

    int o = tid;
    // xp = x @ W_in + b_in   (K=128)
    {
        float acc[PT];
        float bb = b_in[o];
        #pragma unroll
        for (int r = 0; r < PT; r++) acc[r] = bb;
        #pragma unroll 8
        for (int k = 0; k < MEL; k += 4) {
            float w0 = W_in[(k + 0) * Dd + o], w1 = W_in[(k + 1) * Dd + o];
            float w2 = W_in[(k + 2) * Dd + o], w3 = W_in[(k + 3) * Dd + o];
            #pragma unroll
            for (int r = 0; r < PT; r++) {
                float4 xv = *(const float4*)&XR[r][k];
                acc[r] += w0 * xv.x + w1 * xv.y + w2 * xv.z + w3 * xv.w;
            }
        }
        #pragma unroll
        for (int r = 0; r < PT; r++) XP[r][tid] = acc[r];
    }
    __syncthreads();

    // delta dots: WQs[r][i] = (xp_r . u_i) * coef(n,i)
    if (tid < 128) {
        int r = tid >> 5, i = (tid >> 3) & 3, c = tid & 7;
        float s = 0.f;
        const float* xp = XP[r];
        const float* u = UD[i];
        #pragma unroll
        for (int j = 0; j < 24; j++) s += xp[c * 24 + j] * u[c * 24 + j];
        s += __shfl_down(s, 4, 8);
        s += __shfl_down(s, 2, 8);
        s += __shfl_down(s, 1, 8);
        if (c == 0) {
            float coef = (i <= n) ? memcoef(n, i) : 0.f;
            WQs[r * ND + i] = s * coef;
        }
    }
    __syncthreads();

    // x1 = xp + 0.5 * sum_i WQs * err_i
    {
        #pragma unroll
        for (int r = 0; r < PT; r++) {
            float dout = WQs[r * ND + 0] * ED[0][tid] + WQs[r * ND + 1] * ED[1][tid]
                       + WQs[r * ND + 2] * ED[2][tid] + WQs[r * ND + 3] * ED[3][tid];
            X1[r][tid] = XP[r][tid] + 0.5f * dout;
        }
    }
    __syncthreads();

    // x2 = x1 + x1 @ Wavo + b_avo   (K=192)
    {
        float acc[PT];
        float bb = b_avo[o];
        #pragma unroll
        for (int r = 0; r < PT; r++) acc[r] = bb;
        #pragma unroll 8
        for (int k = 0; k < Dd; k += 4) {
            float w0 = Wavo_ws[(k + 0) * Dd + o], w1 = Wavo_ws[(k + 1) * Dd + o];
            float w2 = Wavo_ws[(k + 2) * Dd + o], w3 = Wavo_ws[(k + 3) * Dd + o];
            #pragma unroll
            for (int r = 0; r < PT; r++) {
                float4 xv = *(const float4*)&X1[r][k];
                acc[r] += w0 * xv.x + w1 * xv.y + w2 * xv.z + w3 * xv.w;
            }
        }
        #pragma unroll
        for (int r = 0; r < PT; r++) X2[r][tid] = X1[r][tid] + acc[r];
    }
    __syncthreads();

    // LN1 stats (4 groups of 32 lanes)
    if (tid < 128) {
        int r = tid >> 5, j = tid & 31;
        float s = 0.f, sq = 0.f;
        for (int d = j; d < Dd; d += 32) { float v = X2[r][d]; s += v; sq += v * v; }
        for (int off = 16; off > 0; off >>= 1) {
            s += __shfl_down(s, off, 32); sq += __shfl_down(sq, off, 32);
        }
        if (j == 0) {
            float mean = s / Dd;
            mv[r][0] = mean;
            mv[r][1] = rsqrtf(sq / Dd - mean * mean + EPSc);
        }
    }
    __syncthreads();
    {
        float g = ln1_g[tid], bb = ln1_b[tid];
        #pragma unroll
        for (int r = 0; r < PT; r++)
            LNX[r][tid] = (X2[r][tid] - mv[r][0]) * mv[r][1] * g + bb;
    }
    __syncthreads();

    // pw1 (dual halves) + GLU + dw + bn + silu   (K=192, 2 outputs)
    {
        float aa[PT], gg[PT];
        float ba = pw1_b[o], bg = pw1_b[o + Dd];
        #pragma unroll
        for (int r = 0; r < PT; r++) { aa[r] = ba; gg[r] = bg; }
        #pragma unroll 4
        for (int k = 0; k < Dd; k += 4) {
            float wa0 = pw1_w[(k + 0) * 2 * Dd + o], wg0 = pw1_w[(k + 0) * 2 * Dd + Dd + o];
            float wa1 = pw1_w[(k + 1) * 2 * Dd + o], wg1 = pw1_w[(k + 1) * 2 * Dd + Dd + o];
            float wa2 = pw1_w[(k + 2) * 2 * Dd + o], wg2 = pw1_w[(k + 2) * 2 * Dd + Dd + o];
            float wa3 = pw1_w[(k + 3) * 2 * Dd + o], wg3 = pw1_w[(k + 3) * 2 * Dd + Dd + o];
            #pragma unroll
            for (int r = 0; r < PT; r++) {
                float4 xv = *(const float4*)&LNX[r][k];
                aa[r] += wa0 * xv.x + wa1 * xv.y + wa2 * xv.z + wa3 * xv.w;
                gg[r] += wg0 * xv.x + wg1 * xv.y + wg2 * xv.z + wg3 * xv.w;
            }
        }
        float dww = dw_w[o], dwb = dw_b[o], bns = bn_s[o], bnb = bn_b[o];
        #pragma unroll
        for (int r = 0; r < PT; r++) {
            float h = aa[r] * sigmoidf_(gg[r]);
            h = h * dww + dwb;
            h = h * bns + bnb;
            h = h * sigmoidf_(h);
            HG[r][tid] = h;
        }
    }
    __syncthreads();

    // pw2 + residual -> x3 (direct store)
    {
        float acc[PT];
        float bb = pw2_b[o];
        #pragma unroll
        for (int r = 0; r < PT; r++) acc[r] = bb;
        #pragma unroll 8
        for (int k = 0; k < Dd; k += 4) {
            float w0 = pw2_w[(k + 0) * Dd + o], w1 = pw2_w[(k + 1) * Dd + o];
            float w2 = pw2_w[(k + 2) * Dd + o], w3 = pw2_w[(k + 3) * Dd + o];
            #pragma unroll
            for (int r = 0; r < PT; r++) {
                float4 xv = *(const float4*)&HG[r][k];
                acc[r] += w0 * xv.x + w1 * xv.y + w2 * xv.z + w3 * xv.w;
            }
        }
        #pragma unroll
        for (int r = 0; r < PT; r++)
            x3_ws[((size_t)b * Tt + t0 + r) * Dd + tid] = X2[r][tid] + acc[r];
    }
}

// ---------------------------------------------------------------------------
// theta_projU: grid B*32 = 256 (one update row each).
// k = x3 @ Wk_t, v = x3 @ Wv_t, u = Wq_t @ k  — all k-outer coalesced.
// ---------------------------------------------------------------------------
__global__ __launch_bounds__(192) void theta_projU(
    const float* __restrict__ x3_ws,
    const float* __restrict__ Wk_t, const float* __restrict__ Wv_t,
    const float* __restrict__ WqtT,
    float* __restrict__ Kt_ws, float* __restrict__ Vt_ws,
    float* __restrict__ Ut_ws)
{
    int blk = blockIdx.x, b = blk >> 5, i = blk & 31;
    int tid = threadIdx.x;
    __shared__ float XS[Dd];
    __shared__ float KS[Dd];

    XS[tid] = x3_ws[((size_t)b * Tt + 8 * i) * Dd + tid];
    __syncthreads();

    int o = tid;
    float ak = 0.f, av = 0.f;
    #pragma unroll 4
    for (int k = 0; k < Dd; k += 4) {
        float x0 = XS[k + 0], x1 = XS[k + 1], x2 = XS[k + 2], x3 = XS[k + 3];
        ak += Wk_t[(k + 0) * Dd + o] * x0 + Wk_t[(k + 1) * Dd + o] * x1
            + Wk_t[(k + 2) * Dd + o] * x2 + Wk_t[(k + 3) * Dd + o] * x3;
        av += Wv_t[(k + 0) * Dd + o] * x0 + Wv_t[(k + 1) * Dd + o] * x1
            + Wv_t[(k + 2) * Dd + o] * x2 + Wv_t[(k + 3) * Dd + o] * x3;
    }
    Kt_ws[(b * NT + i) * Dd + o] = ak;
    Vt_ws[(b * NT + i) * Dd + o] = av;
    KS[o] = ak;
    __syncthreads();

    float au = 0.f;
    #pragma unroll 8
    for (int k = 0; k < Dd; k += 4) {
        au += WqtT[(k + 0) * Dd + o] * KS[k + 0];
        au += WqtT[(k + 1) * Dd + o] * KS[k + 1];
        au += WqtT[(k + 2) * Dd + o] * KS[k + 2];
        au += WqtT[(k + 3) * Dd + o] * KS[k + 3];
    }
    Ut_ws[(b * NT + i) * Dd + o] = au;
}

// ---------------------------------------------------------------------------
// theta_solve: grid B = 8. Gram 32x32 + 31-step err recurrence; rewrites
// Vt_ws in place (v -> err). One barrier per step.
// ---------------------------------------------------------------------------
__global__ __launch_bounds__(192) void theta_solve(
    const float* __restrict__ Kt_ws, float* __restrict__ Vt_ws)
{
    int b = blockIdx.x, tid = threadIdx.x;
    __shared__ __align__(16) float K[NT][PADD], E[NT][PADD];
    __shared__ float G[NT * NT], mc[NT * NT];

    for (int q = tid; q < NT * 48; q += 192) {
        int i = q / 48, c = q - i * 48;
        ((float4*)K[i])[c] = ((const float4*)&Kt_ws[(b * NT + i) * Dd])[c];
        ((float4*)E[i])[c] = ((const float4*)&Vt_ws[(b * NT + i) * Dd])[c];
    }
    if (tid < NT) {
        int i = tid;
        float m = 0.f, pw = LRc;
        for (int nn = 0; nn < NT; nn++) {
            float v;
            if (nn < i) v = 0.f;
            else if (nn == i) { m = LRc; v = m; }
            else { pw *= ETAc; m = MDEC * m + pw; v = m; }
            mc[nn * NT + i] = v;
        }
    }
    __syncthreads();
    for (int p = tid; p < NT * NT; p += 192) {
        int i = p >> 5, j = p & 31;
        const float4* ki = (const float4*)K[i];
        const float4* kj = (const float4*)K[j];
        float s = 0.f;
        #pragma unroll 4
        for (int kk = 0; kk < 48; kk++) s += dot4(ki[kk], kj[kk]);
        G[p] = s;
    }
    __syncthreads();
    for (int i = 1; i < NT; i++) {
        float acc = E[i][tid];
        #pragma unroll 4
        for (int m = 0; m < i; m++)
            acc -= mc[(i - 1) * NT + m] * G[i * NT + m] * E[m][tid];
        E[i][tid] = acc;             // row i written; peers read rows < i only
        __syncthreads();
    }
    for (int i = 0; i < NT; i++) Vt_ws[(b * NT + i) * Dd + tid] = E[i][tid];
}

// ---------------------------------------------------------------------------
// retrieve: grid B*32 (8 rows/block), 256 threads. (verified R4 body; Et->Vt)
// ---------------------------------------------------------------------------
__global__ __launch_bounds__(256) void retrieve(
    const float* __restrict__ x3_ws, const float* __restrict__ Ut_ws,
    const float* __restrict__ Et_ws, const float* __restrict__ ln2_g,
    const float* __restrict__ ln2_b, float* __restrict__ pooled)
{
    int blk = blockIdx.x, b = blk >> 5, tile = blk & 31;
    int t0 = tile * RTT, n = tile;
    int tid = threadIdx.x;

    __shared__ __align__(16) float UT[NT][PADD];
    __shared__ __align__(16) float XS[RTT][PADD];
    __shared__ float WQ[RTT * NT];
    __shared__ float mv[RTT][2];

    for (int q = tid; q < NT * 48; q += 256) {
        int i = q / 48, c = q - i * 48;
        ((float4*)UT[i])[c] = ((const float4*)&Ut_ws[(b * NT + i) * Dd])[c];
    }
    for (int q = tid; q < RTT * 48; q += 256) {
        int r = q / 48, c = q - r * 48;
        ((float4*)XS[r])[c] = ((const float4*)&x3_ws[((size_t)b * Tt + t0 + r) * Dd])[c];
    }
    __syncthreads();

    // dots: tid = r*32 + i ; w[r][i] = (x3_r . u~_i) * coef
    {
        int r = tid >> 5, i = tid & 31;
        const float4* u4 = (const float4*)UT[i];
        const float4* x4 = (const float4*)XS[r];
        float s = 0.f;
        #pragma unroll 8
        for (int kk = 0; kk < 48; kk++) s += dot4(u4[kk], x4[kk]);
        float coef = (i <= n) ? memcoef(n, i) : 0.f;
        WQ[tid] = s * coef;
    }
    __syncthreads();

    // x4 = x3 + 0.5 * sum_i WQ * err_i   (err streamed coalesced from global)
    if (tid < Dd) {
        float acc[RTT] = {};
        #pragma unroll 4
        for (int i = 0; i < NT; i++) {
            float e = Et_ws[(b * NT + i) * Dd + tid];
            #pragma unroll
            for (int r = 0; r < RTT; r++) acc[r] += WQ[r * NT + i] * e;
        }
        #pragma unroll
        for (int r = 0; r < RTT; r++) XS[r][tid] += 0.5f * acc[r];
    }
    __syncthreads();

    // LN2 stats
    {
        int r = tid >> 5, j = tid & 31;
        float s = 0.f, sq = 0.f;
        for (int d = j; d < Dd; d += 32) { float v = XS[r][d]; s += v; sq += v * v; }
        for (int off = 16; off > 0; off >>= 1) {
            s += __shfl_down(s, off, 32); sq += __shfl_down(sq, off, 32);
        }
        if (j == 0) {
            float mean = s / Dd;
            mv[r][0] = mean;
            mv[r][1] = rsqrtf(sq / Dd - mean * mean + EPSc);
        }
    }
    __syncthreads();

    if (tid < Dd) {
        float g = ln2_g[tid], bb = ln2_b[tid];
        float sum = 0.f;
        #pragma unroll
        for (int r = 0; r < RTT; r++)
            sum += (XS[r][tid] - mv[r][0]) * mv[r][1] * g + bb;
        atomicAdd(&pooled[b * Dd + tid], sum);
    }
}

// ---------------------------------------------------------------------------
__global__ __launch_bounds__(192) void head(
    const float* __restrict__ pooled, const float* __restrict__ Wc,
    const float* __restrict__ bc, float* __restrict__ out)
{
    int tid = threadIdx.x;
    if (tid < Bb * NCc) {
        int b = tid / NCc, c = tid - b * NCc;
        float s = 0.f;
        for (int d = 0; d < Dd; d++) s += pooled[b * Dd + d] * Wc[d * NCc + c];
        out[tid] = s * (1.0f / Tt) + bc[c];
    }
}

extern "C" void kernel_launch(void* const* d_in, const int* in_sizes, int n_in,
                              void* d_out, int out_size, void* d_ws, size_t ws_size,
                              hipStream_t stream) {
    const float* x     = (const float*)d_in[0];
    const float* W_in  = (const float*)d_in[1];
    const float* b_in  = (const float*)d_in[2];
    const float* Wv_a  = (const float*)d_in[3];
    const float* bv_a  = (const float*)d_in[4];
    const float* Wo_a  = (const float*)d_in[5];
    const float* bo_a  = (const float*)d_in[6];
    const float* ln1_g = (const float*)d_in[7];
    const float* ln1_b = (const float*)d_in[8];
    const float* pw1_w = (const float*)d_in[9];
    const float* pw1_b = (const float*)d_in[10];
    const float* dw_w  = (const float*)d_in[11];
    const float* dw_b  = (const float*)d_in[12];
    const float* bn_s  = (const float*)d_in[13];
    const float* bn_b  = (const float*)d_in[14];
    const float* pw2_w = (const float*)d_in[15];
    const float* pw2_b = (const float*)d_in[16];
    const float* Wk_t  = (const float*)d_in[17];
    const float* Wv_t  = (const float*)d_in[18];
    const float* Wq_t  = (const float*)d_in[19];
    const float* Wk_d  = (const float*)d_in[20];
    const float* Wv_d  = (const float*)d_in[21];
    const float* Wq_d  = (const float*)d_in[22];
    const float* ln2_g = (const float*)d_in[23];
    const float* ln2_b = (const float*)d_in[24];
    const float* Wc    = (const float*)d_in[25];
    const float* bc    = (const float*)d_in[26];

    float* ws = (float*)d_ws;
    size_t off = 0;
    float* x3_ws   = ws + off; off += (size_t)Bb * Tt * Dd;
    float* Kd_ws   = ws + off; off += Bb * ND * Dd;
    float* Vd_ws   = ws + off; off += Bb * ND * Dd;   // becomes err after delta_solve
    float* Ud_ws   = ws + off; off += Bb * ND * Dd;
    float* Kt_ws   = ws + off; off += Bb * NT * Dd;
    float* Vt_ws   = ws + off; off += Bb * NT * Dd;   // becomes err after theta_solve
    float* Ut_ws   = ws + off; off += Bb * NT * Dd;
    float* pooled  = ws + off; off += Bb * Dd;
    float* Wavo_ws = ws + off; off += Dd * Dd;
    float* WqtT    = ws + off; off += Dd * Dd;
    float* WqdT    = ws + off; off += Dd * Dd;
    float* b_avo   = ws + off; off += Dd;

    prep<<<322, 192, 0, stream>>>(
        Wv_a, Wo_a, bv_a, bo_a, Wq_t, Wq_d,
        x, W_in, b_in, Wk_d, Wv_d,
        Wavo_ws, b_avo, WqtT, WqdT, Kd_ws, Vd_ws, pooled);
    delta_solve<<<Bb * 5, 192, 0, stream>>>(WqdT, Kd_ws, Vd_ws, Ud_ws);
    pipeline<<<Bb * PTILES, 192, 0, stream>>>(
        x, W_in, b_in, ln1_g, ln1_b, pw1_w, pw1_b, dw_w, dw_b,
        bn_s, bn_b, pw2_w, pw2_b, Wavo_ws, b_avo, Vd_ws, Ud_ws, x3_ws);
    theta_projU<<<Bb * NT, 192, 0, stream>>>(
        x3_ws, Wk_t, Wv_t, WqtT, Kt_ws, Vt_ws, Ut_ws);
    theta_solve<<<Bb, 192, 0, stream>>>(Kt_ws, Vt_ws);
    retrieve<<<Bb * 32, 256, 0, stream>>>(
        x3_ws, Ut_ws, Vt_ws, ln2_g, ln2_b, pooled);
    head<<<1, 192, 0, stream>>>(pooled, Wc, bc, (float*)d_out);
}